// Round 1
// baseline (9553.465 us; speedup 1.0000x reference)
//
#include <hip/hip_runtime.h>
#include <cstdint>

#define NHEAD 16
#define DKK 64
#define BB 2
#define SS 2048
#define DMODEL 1024

// ---------------------------------------------------------------------------
// GEMM: Y = X @ W^T (+ bias). X [M,1024] row-major, W [N,1024] row-major
// (torch Linear weight layout), both K-contiguous -> coalesced staging.
// Tile 64x64, BK=64, 256 threads (16x16), 4x4 microtile.
// LDS layout: element (row i, k d) stored at i*64 + ((d/4 ^ (i>>2))*4 + d%4)
// -> float4 XOR swizzle kills the B-operand same-column bank conflicts.
// MODE 0: scatter output to [B,H,S,DK] (head split).
// MODE 1: row-major [M,N] with bias add.
// ---------------------------------------------------------------------------
template <int MODE>
__global__ __launch_bounds__(256, 4) void gemm_xwt(
    const float* __restrict__ X, const float* __restrict__ W,
    const float* __restrict__ bias, float* __restrict__ Y) {
  __shared__ float As[64 * 64];
  __shared__ float Bs[64 * 64];

  const int tid = threadIdx.x;
  const int tx = tid & 15;
  const int ty = tid >> 4;
  const int n0 = blockIdx.x * 64;  // x = N tiles (16): consecutive blocks share X tile
  const int m0 = blockIdx.y * 64;  // y = M tiles (64)

  const int srow = tid >> 4;   // staging row base 0..15
  const int sslot = tid & 15;  // float4 slot 0..15

  float acc[4][4] = {};

  for (int k0 = 0; k0 < DMODEL; k0 += 64) {
    __syncthreads();
#pragma unroll
    for (int rep = 0; rep < 4; ++rep) {
      const int i = rep * 16 + srow;
      const int ssw = ((sslot ^ (i >> 2)) & 15) << 2;
      const float4 a = *(const float4*)&X[(size_t)(m0 + i) * DMODEL + k0 + sslot * 4];
      *(float4*)&As[i * 64 + ssw] = a;
      const float4 b = *(const float4*)&W[(size_t)(n0 + i) * DMODEL + k0 + sslot * 4];
      *(float4*)&Bs[i * 64 + ssw] = b;
    }
    __syncthreads();
#pragma unroll
    for (int d4 = 0; d4 < 16; ++d4) {
      float4 av[4], bv[4];
#pragma unroll
      for (int r = 0; r < 4; ++r) {
        av[r] = *(const float4*)&As[(ty * 4 + r) * 64 + (((d4 ^ ty) & 15) << 2)];
        bv[r] = *(const float4*)&Bs[(tx * 4 + r) * 64 + (((d4 ^ tx) & 15) << 2)];
      }
#pragma unroll
      for (int r = 0; r < 4; ++r)
#pragma unroll
        for (int c = 0; c < 4; ++c)
          acc[r][c] += av[r].x * bv[c].x + av[r].y * bv[c].y +
                       av[r].z * bv[c].z + av[r].w * bv[c].w;
    }
  }

  if (MODE == 0) {
    // scatter to [B, H, S, DK]
    const int n = n0 + tx * 4;
    const int h = n >> 6;
    const int dk = n & 63;
#pragma unroll
    for (int r = 0; r < 4; ++r) {
      const int m = m0 + ty * 4 + r;
      const int b = m >> 11;
      const int s = m & (SS - 1);
      float4 v = make_float4(acc[r][0], acc[r][1], acc[r][2], acc[r][3]);
      *(float4*)&Y[(((size_t)b * NHEAD + h) * SS + s) * DKK + dk] = v;
    }
  } else {
    const int n = n0 + tx * 4;
    const float4 bv = *(const float4*)&bias[n];
#pragma unroll
    for (int r = 0; r < 4; ++r) {
      const int m = m0 + ty * 4 + r;
      float4 v = make_float4(acc[r][0] + bv.x, acc[r][1] + bv.y,
                             acc[r][2] + bv.z, acc[r][3] + bv.w);
      *(float4*)&Y[(size_t)m * DMODEL + n] = v;
    }
  }
}

// ---------------------------------------------------------------------------
// Flash attention fp32. One block per (64 q-rows, b*H+h).
// Q,K,V in [B,H,S,DK]. Online softmax in base 2 (v_exp_f32 is 2^x);
// 1/sqrt(Dk)*log2(e) folded into Q at staging.
// Output written to [B, S, D] (heads re-interleaved) for the final GEMM.
// ---------------------------------------------------------------------------
__global__ __launch_bounds__(256, 2) void attn_fwd(
    const float* __restrict__ Q, const float* __restrict__ K,
    const float* __restrict__ V, float* __restrict__ AO) {
  __shared__ float Qs[64 * 64];
  __shared__ float Ks[64 * 64];
  __shared__ float Vs[64 * 64];
  __shared__ float Ps[64 * 64];

  const int tid = threadIdx.x;
  const int tx = tid & 15;
  const int ty = tid >> 4;
  const int bh = blockIdx.y;  // b*16 + h
  const int q0 = blockIdx.x * 64;

  const float* Qp = Q + ((size_t)bh * SS + q0) * DKK;
  const float* Kp = K + (size_t)bh * SS * DKK;
  const float* Vp = V + (size_t)bh * SS * DKK;

  const int srow = tid >> 4;
  const int sslot = tid & 15;
  const float qscale = 0.125f * 1.4426950408889634f;  // 1/sqrt(64) * log2(e)

  // stage Q once, pre-scaled, swizzled
#pragma unroll
  for (int rep = 0; rep < 4; ++rep) {
    const int i = rep * 16 + srow;
    const int ssw = ((sslot ^ (i >> 2)) & 15) << 2;
    float4 q = *(const float4*)&Qp[(size_t)i * DKK + sslot * 4];
    q.x *= qscale; q.y *= qscale; q.z *= qscale; q.w *= qscale;
    *(float4*)&Qs[i * 64 + ssw] = q;
  }

  float oacc[4][4] = {};
  float mrun[4] = {-1e30f, -1e30f, -1e30f, -1e30f};
  float lrun[4] = {0.f, 0.f, 0.f, 0.f};

  for (int k0 = 0; k0 < SS; k0 += 64) {
    __syncthreads();
#pragma unroll
    for (int rep = 0; rep < 4; ++rep) {
      const int i = rep * 16 + srow;
      const int ssw = ((sslot ^ (i >> 2)) & 15) << 2;
      *(float4*)&Ks[i * 64 + ssw] =
          *(const float4*)&Kp[(size_t)(k0 + i) * DKK + sslot * 4];
      *(float4*)&Vs[i * 64 + ssw] =
          *(const float4*)&Vp[(size_t)(k0 + i) * DKK + sslot * 4];
    }
    __syncthreads();

    // S = (Q*qscale) @ K^T, 4x4 per thread
    float sacc[4][4] = {};
#pragma unroll
    for (int d4 = 0; d4 < 16; ++d4) {
      float4 qv[4], kv[4];
#pragma unroll
      for (int r = 0; r < 4; ++r) {
        qv[r] = *(const float4*)&Qs[(ty * 4 + r) * 64 + (((d4 ^ ty) & 15) << 2)];
        kv[r] = *(const float4*)&Ks[(tx * 4 + r) * 64 + (((d4 ^ tx) & 15) << 2)];
      }
#pragma unroll
      for (int r = 0; r < 4; ++r)
#pragma unroll
        for (int c = 0; c < 4; ++c)
          sacc[r][c] += qv[r].x * kv[c].x + qv[r].y * kv[c].y +
                        qv[r].z * kv[c].z + qv[r].w * kv[c].w;
    }

    // online softmax (base-2); rows live in 16 consecutive lanes (same ty)
#pragma unroll
    for (int r = 0; r < 4; ++r) {
      float tmax = fmaxf(fmaxf(sacc[r][0], sacc[r][1]),
                         fmaxf(sacc[r][2], sacc[r][3]));
#pragma unroll
      for (int msk = 1; msk < 16; msk <<= 1)
        tmax = fmaxf(tmax, __shfl_xor(tmax, msk, 64));
      const float mnew = fmaxf(mrun[r], tmax);
      const float corr = exp2f(mrun[r] - mnew);
      mrun[r] = mnew;
      float psum = 0.f;
#pragma unroll
      for (int c = 0; c < 4; ++c) {
        const float p = exp2f(sacc[r][c] - mnew);
        sacc[r][c] = p;
        psum += p;
      }
#pragma unroll
      for (int msk = 1; msk < 16; msk <<= 1)
        psum += __shfl_xor(psum, msk, 64);
      lrun[r] = lrun[r] * corr + psum;
#pragma unroll
      for (int c = 0; c < 4; ++c) oacc[r][c] *= corr;
      *(float4*)&Ps[(ty * 4 + r) * 64 + tx * 4] =
          make_float4(sacc[r][0], sacc[r][1], sacc[r][2], sacc[r][3]);
    }
    __syncthreads();

    // O += P @ V  (reduce over j); V swizzle slot = tx ^ (j>>2) = tx ^ j4
#pragma unroll
    for (int j4 = 0; j4 < 16; ++j4) {
      float4 vv[4];
#pragma unroll
      for (int jj = 0; jj < 4; ++jj)
        vv[jj] = *(const float4*)&Vs[(j4 * 4 + jj) * 64 + (((tx ^ j4) & 15) << 2)];
#pragma unroll
      for (int r = 0; r < 4; ++r) {
        const float4 p4 = *(const float4*)&Ps[(ty * 4 + r) * 64 + j4 * 4];
        oacc[r][0] += p4.x * vv[0].x + p4.y * vv[1].x + p4.z * vv[2].x + p4.w * vv[3].x;
        oacc[r][1] += p4.x * vv[0].y + p4.y * vv[1].y + p4.z * vv[2].y + p4.w * vv[3].y;
        oacc[r][2] += p4.x * vv[0].z + p4.y * vv[1].z + p4.z * vv[2].z + p4.w * vv[3].z;
        oacc[r][3] += p4.x * vv[0].w + p4.y * vv[1].w + p4.z * vv[2].w + p4.w * vv[3].w;
      }
    }
  }

  // normalize + write to [B, S, D] with heads interleaved
  const int b = bh >> 4;
  const int h = bh & 15;
#pragma unroll
  for (int r = 0; r < 4; ++r) {
    const float inv = 1.0f / lrun[r];
    float4 o = make_float4(oacc[r][0] * inv, oacc[r][1] * inv,
                           oacc[r][2] * inv, oacc[r][3] * inv);
    *(float4*)&AO[((size_t)b * SS + q0 + ty * 4 + r) * DMODEL + h * DKK + tx * 4] = o;
  }
}

extern "C" void kernel_launch(void* const* d_in, const int* in_sizes, int n_in,
                              void* d_out, int out_size, void* d_ws,
                              size_t ws_size, hipStream_t stream) {
  const float* query = (const float*)d_in[0];
  const float* key   = (const float*)d_in[1];
  const float* value = (const float*)d_in[2];
  const float* w_q   = (const float*)d_in[3];
  const float* w_k   = (const float*)d_in[4];
  const float* w_v   = (const float*)d_in[5];
  const float* w_o   = (const float*)d_in[6];
  const float* b_o   = (const float*)d_in[7];
  float* out = (float*)d_out;

  const size_t per = (size_t)BB * NHEAD * SS * DKK;  // 4,194,304 floats
  float* Qb = (float*)d_ws;     // [B,H,S,DK]
  float* Kb = Qb + per;
  float* Vb = Kb + per;
  float* AO = Vb + per;         // [B,S,D]

  dim3 blk(256);
  dim3 gproj(DMODEL / 64, (BB * SS) / 64);  // (16, 64)
  gemm_xwt<0><<<gproj, blk, 0, stream>>>(query, w_q, nullptr, Qb);
  gemm_xwt<0><<<gproj, blk, 0, stream>>>(key,   w_k, nullptr, Kb);
  gemm_xwt<0><<<gproj, blk, 0, stream>>>(value, w_v, nullptr, Vb);

  dim3 gattn(SS / 64, BB * NHEAD);  // (32, 32)
  attn_fwd<<<gattn, blk, 0, stream>>>(Qb, Kb, Vb, AO);

  gemm_xwt<1><<<gproj, blk, 0, stream>>>(AO, w_o, b_o, out);
}

// Round 2
// 1458.831 us; speedup vs baseline: 6.5487x; 6.5487x over previous
//
#include <hip/hip_runtime.h>
#include <hip/hip_bf16.h>
#include <cstdint>

#define NHEAD 16
#define DKK 64
#define BB 2
#define SS 2048
#define DMODEL 1024

typedef __attribute__((ext_vector_type(8))) short s16x8;
typedef __attribute__((ext_vector_type(4))) float f32x4;

__device__ __forceinline__ void split1(float x, short& h, short& l) {
  __hip_bfloat16 hb = __float2bfloat16(x);
  float hf = __bfloat162float(hb);
  __hip_bfloat16 lb = __float2bfloat16(x - hf);
  h = *reinterpret_cast<short*>(&hb);
  l = *reinterpret_cast<short*>(&lb);
}

// ---------------------------------------------------------------------------
// Pre-split fp32 -> (hi, lo) bf16 pair. n4 = elements/4.
// ---------------------------------------------------------------------------
__global__ __launch_bounds__(256) void split_f32(
    const float* __restrict__ x, short* __restrict__ hi,
    short* __restrict__ lo, int n4) {
  int i = blockIdx.x * blockDim.x + threadIdx.x;
  if (i >= n4) return;
  float4 v = ((const float4*)x)[i];
  short4 h, l;
  split1(v.x, h.x, l.x);
  split1(v.y, h.y, l.y);
  split1(v.z, h.z, l.z);
  split1(v.w, h.w, l.w);
  *(short4*)&hi[i * 4] = h;
  *(short4*)&lo[i * 4] = l;
}

// ---------------------------------------------------------------------------
// Split-bf16 MFMA GEMM: Y = (Ahi+Alo) @ (Bhi+Blo)^T (+bias).
// A [M=4096, K=1024] bf16 row-major (hi/lo), B [N=1024, K] bf16 row-major.
// Tile BM=128, BN=64, BK=64. 256 threads = 4 waves (2M x 2N), each wave 64x32.
// LDS rows of 64 bf16 (128B); 16B-slot XOR swizzle: slot ^= (row & 7)
// -> frag ds_read_b128 is 2-way at worst (free). 48 KiB LDS.
// MFMA 16x16x32_bf16, 3 products per fragment pair, one fp32 accumulator.
// MODE 0: scatter fp32 to [B,H,S,DK]. MODE 1: fp32 [M,N] + bias.
// ---------------------------------------------------------------------------
template <int MODE>
__global__ __launch_bounds__(256) void gemm_split_mfma(
    const short* __restrict__ Ahi, const short* __restrict__ Alo,
    const short* __restrict__ Bhi, const short* __restrict__ Blo,
    const float* __restrict__ bias, float* __restrict__ Y) {
  __shared__ short lds[(128 + 128 + 64 + 64) * 64];
  short* Ah = lds;
  short* Al = lds + 128 * 64;
  short* Bh = lds + 256 * 64;
  short* Bl = lds + 320 * 64;

  const int tid = threadIdx.x;
  const int lane = tid & 63;
  const int w = tid >> 6;
  const int wm = (w >> 1) * 64;
  const int wn = (w & 1) * 32;
  const int m0 = blockIdx.y * 128;
  const int n0 = blockIdx.x * 64;

  f32x4 acc[4][2];
#pragma unroll
  for (int r = 0; r < 4; ++r)
#pragma unroll
    for (int c = 0; c < 2; ++c) acc[r][c] = (f32x4){0.f, 0.f, 0.f, 0.f};

  for (int k0 = 0; k0 < DMODEL; k0 += 64) {
    __syncthreads();
    // stage A (128 rows x 8 slots of 16B) hi+lo
#pragma unroll
    for (int i = 0; i < 4; ++i) {
      const int g = tid + i * 256;
      const int row = g >> 3;
      const int slot = g & 7;
      const int ssw = slot ^ (row & 7);
      const size_t goff = (size_t)(m0 + row) * DMODEL + k0 + slot * 8;
      *(s16x8*)&Ah[row * 64 + ssw * 8] = *(const s16x8*)&Ahi[goff];
      *(s16x8*)&Al[row * 64 + ssw * 8] = *(const s16x8*)&Alo[goff];
    }
    // stage B (64 rows x 8 slots) hi+lo
#pragma unroll
    for (int i = 0; i < 2; ++i) {
      const int g = tid + i * 256;
      const int row = g >> 3;
      const int slot = g & 7;
      const int ssw = slot ^ (row & 7);
      const size_t goff = (size_t)(n0 + row) * DMODEL + k0 + slot * 8;
      *(s16x8*)&Bh[row * 64 + ssw * 8] = *(const s16x8*)&Bhi[goff];
      *(s16x8*)&Bl[row * 64 + ssw * 8] = *(const s16x8*)&Blo[goff];
    }
    __syncthreads();

#pragma unroll
    for (int ks = 0; ks < 2; ++ks) {
      const int kslot = (lane >> 4) + ks * 4;
      s16x8 ah[4], al[4], bh[2], bl[2];
#pragma unroll
      for (int r = 0; r < 4; ++r) {
        const int row = wm + r * 16 + (lane & 15);
        const int ssw = (kslot ^ (row & 7)) * 8;
        ah[r] = *(const s16x8*)&Ah[row * 64 + ssw];
        al[r] = *(const s16x8*)&Al[row * 64 + ssw];
      }
#pragma unroll
      for (int c = 0; c < 2; ++c) {
        const int row = wn + c * 16 + (lane & 15);
        const int ssw = (kslot ^ (row & 7)) * 8;
        bh[c] = *(const s16x8*)&Bh[row * 64 + ssw];
        bl[c] = *(const s16x8*)&Bl[row * 64 + ssw];
      }
#pragma unroll
      for (int r = 0; r < 4; ++r)
#pragma unroll
        for (int c = 0; c < 2; ++c) {
          acc[r][c] = __builtin_amdgcn_mfma_f32_16x16x32_bf16(al[r], bh[c], acc[r][c], 0, 0, 0);
          acc[r][c] = __builtin_amdgcn_mfma_f32_16x16x32_bf16(ah[r], bl[c], acc[r][c], 0, 0, 0);
          acc[r][c] = __builtin_amdgcn_mfma_f32_16x16x32_bf16(ah[r], bh[c], acc[r][c], 0, 0, 0);
        }
    }
  }

  // epilogue: D col = lane&15, row = (lane>>4)*4 + j   [m89-verified]
  const int lrow = (lane >> 4) * 4;
  const int lcol = lane & 15;
#pragma unroll
  for (int r = 0; r < 4; ++r)
#pragma unroll
    for (int c = 0; c < 2; ++c) {
      const int n = n0 + wn + c * 16 + lcol;
#pragma unroll
      for (int j = 0; j < 4; ++j) {
        const int m = m0 + wm + r * 16 + lrow + j;
        const float v = acc[r][c][j];
        if (MODE == 0) {
          Y[((size_t)((m >> 11) * NHEAD + (n >> 6)) * SS + (m & (SS - 1))) * DKK + (n & 63)] = v;
        } else {
          Y[(size_t)m * DMODEL + n] = v + bias[n];
        }
      }
    }
}

// ---------------------------------------------------------------------------
// Flash attention fp32 (unchanged from passing version except epilogue now
// emits split bf16 hi/lo for the MFMA O-projection).
// ---------------------------------------------------------------------------
__global__ __launch_bounds__(256, 2) void attn_fwd(
    const float* __restrict__ Q, const float* __restrict__ K,
    const float* __restrict__ V, short* __restrict__ AOhi,
    short* __restrict__ AOlo) {
  __shared__ float Qs[64 * 64];
  __shared__ float Ks[64 * 64];
  __shared__ float Vs[64 * 64];
  __shared__ float Ps[64 * 64];

  const int tid = threadIdx.x;
  const int tx = tid & 15;
  const int ty = tid >> 4;
  const int bh = blockIdx.y;
  const int q0 = blockIdx.x * 64;

  const float* Qp = Q + ((size_t)bh * SS + q0) * DKK;
  const float* Kp = K + (size_t)bh * SS * DKK;
  const float* Vp = V + (size_t)bh * SS * DKK;

  const int srow = tid >> 4;
  const int sslot = tid & 15;
  const float qscale = 0.125f * 1.4426950408889634f;

#pragma unroll
  for (int rep = 0; rep < 4; ++rep) {
    const int i = rep * 16 + srow;
    const int ssw = ((sslot ^ (i >> 2)) & 15) << 2;
    float4 q = *(const float4*)&Qp[(size_t)i * DKK + sslot * 4];
    q.x *= qscale; q.y *= qscale; q.z *= qscale; q.w *= qscale;
    *(float4*)&Qs[i * 64 + ssw] = q;
  }

  float oacc[4][4] = {};
  float mrun[4] = {-1e30f, -1e30f, -1e30f, -1e30f};
  float lrun[4] = {0.f, 0.f, 0.f, 0.f};

  for (int k0 = 0; k0 < SS; k0 += 64) {
    __syncthreads();
#pragma unroll
    for (int rep = 0; rep < 4; ++rep) {
      const int i = rep * 16 + srow;
      const int ssw = ((sslot ^ (i >> 2)) & 15) << 2;
      *(float4*)&Ks[i * 64 + ssw] =
          *(const float4*)&Kp[(size_t)(k0 + i) * DKK + sslot * 4];
      *(float4*)&Vs[i * 64 + ssw] =
          *(const float4*)&Vp[(size_t)(k0 + i) * DKK + sslot * 4];
    }
    __syncthreads();

    float sacc[4][4] = {};
#pragma unroll
    for (int d4 = 0; d4 < 16; ++d4) {
      float4 qv[4], kv[4];
#pragma unroll
      for (int r = 0; r < 4; ++r) {
        qv[r] = *(const float4*)&Qs[(ty * 4 + r) * 64 + (((d4 ^ ty) & 15) << 2)];
        kv[r] = *(const float4*)&Ks[(tx * 4 + r) * 64 + (((d4 ^ tx) & 15) << 2)];
      }
#pragma unroll
      for (int r = 0; r < 4; ++r)
#pragma unroll
        for (int c = 0; c < 4; ++c)
          sacc[r][c] += qv[r].x * kv[c].x + qv[r].y * kv[c].y +
                        qv[r].z * kv[c].z + qv[r].w * kv[c].w;
    }

#pragma unroll
    for (int r = 0; r < 4; ++r) {
      float tmax = fmaxf(fmaxf(sacc[r][0], sacc[r][1]),
                         fmaxf(sacc[r][2], sacc[r][3]));
#pragma unroll
      for (int msk = 1; msk < 16; msk <<= 1)
        tmax = fmaxf(tmax, __shfl_xor(tmax, msk, 64));
      const float mnew = fmaxf(mrun[r], tmax);
      const float corr = exp2f(mrun[r] - mnew);
      mrun[r] = mnew;
      float psum = 0.f;
#pragma unroll
      for (int c = 0; c < 4; ++c) {
        const float p = exp2f(sacc[r][c] - mnew);
        sacc[r][c] = p;
        psum += p;
      }
#pragma unroll
      for (int msk = 1; msk < 16; msk <<= 1)
        psum += __shfl_xor(psum, msk, 64);
      lrun[r] = lrun[r] * corr + psum;
#pragma unroll
      for (int c = 0; c < 4; ++c) oacc[r][c] *= corr;
      *(float4*)&Ps[(ty * 4 + r) * 64 + tx * 4] =
          make_float4(sacc[r][0], sacc[r][1], sacc[r][2], sacc[r][3]);
    }
    __syncthreads();

#pragma unroll
    for (int j4 = 0; j4 < 16; ++j4) {
      float4 vv[4];
#pragma unroll
      for (int jj = 0; jj < 4; ++jj)
        vv[jj] = *(const float4*)&Vs[(j4 * 4 + jj) * 64 + (((tx ^ j4) & 15) << 2)];
#pragma unroll
      for (int r = 0; r < 4; ++r) {
        const float4 p4 = *(const float4*)&Ps[(ty * 4 + r) * 64 + j4 * 4];
        oacc[r][0] += p4.x * vv[0].x + p4.y * vv[1].x + p4.z * vv[2].x + p4.w * vv[3].x;
        oacc[r][1] += p4.x * vv[0].y + p4.y * vv[1].y + p4.z * vv[2].y + p4.w * vv[3].y;
        oacc[r][2] += p4.x * vv[0].z + p4.y * vv[1].z + p4.z * vv[2].z + p4.w * vv[3].z;
        oacc[r][3] += p4.x * vv[0].w + p4.y * vv[1].w + p4.z * vv[2].w + p4.w * vv[3].w;
      }
    }
  }

  const int b = bh >> 4;
  const int h = bh & 15;
#pragma unroll
  for (int r = 0; r < 4; ++r) {
    const float inv = 1.0f / lrun[r];
    const size_t base =
        ((size_t)b * SS + q0 + ty * 4 + r) * DMODEL + h * DKK + tx * 4;
    short4 hv, lv;
    split1(oacc[r][0] * inv, hv.x, lv.x);
    split1(oacc[r][1] * inv, hv.y, lv.y);
    split1(oacc[r][2] * inv, hv.z, lv.z);
    split1(oacc[r][3] * inv, hv.w, lv.w);
    *(short4*)&AOhi[base] = hv;
    *(short4*)&AOlo[base] = lv;
  }
}

extern "C" void kernel_launch(void* const* d_in, const int* in_sizes, int n_in,
                              void* d_out, int out_size, void* d_ws,
                              size_t ws_size, hipStream_t stream) {
  const float* query = (const float*)d_in[0];
  const float* key   = (const float*)d_in[1];
  const float* value = (const float*)d_in[2];
  const float* w_q   = (const float*)d_in[3];
  const float* w_k   = (const float*)d_in[4];
  const float* w_v   = (const float*)d_in[5];
  const float* w_o   = (const float*)d_in[6];
  const float* b_o   = (const float*)d_in[7];
  float* out = (float*)d_out;

  char* ws = (char*)d_ws;
  const size_t per = (size_t)BB * NHEAD * SS * DKK;  // 4,194,304 elements
  float* Qb = (float*)ws;
  float* Kb = Qb + per;
  float* Vb = Kb + per;
  short* Xhi = (short*)(ws + 3 * per * sizeof(float));  // 50331648
  short* Xlo = Xhi + per;
  short* Whi = Xlo + per;            // offset 67108864
  short* Wlo = Whi + DMODEL * DMODEL;

  const int nX4 = (int)(per / 4);               // 1048576
  const int nW4 = (DMODEL * DMODEL) / 4;        // 262144
  dim3 blk(256);
  dim3 ggemm(DMODEL / 64, (BB * SS) / 128);     // (16, 32)

  // Q projection
  split_f32<<<nX4 / 256, blk, 0, stream>>>(query, Xhi, Xlo, nX4);
  split_f32<<<nW4 / 256, blk, 0, stream>>>(w_q, Whi, Wlo, nW4);
  gemm_split_mfma<0><<<ggemm, blk, 0, stream>>>(Xhi, Xlo, Whi, Wlo, nullptr, Qb);
  // K projection
  split_f32<<<nX4 / 256, blk, 0, stream>>>(key, Xhi, Xlo, nX4);
  split_f32<<<nW4 / 256, blk, 0, stream>>>(w_k, Whi, Wlo, nW4);
  gemm_split_mfma<0><<<ggemm, blk, 0, stream>>>(Xhi, Xlo, Whi, Wlo, nullptr, Kb);
  // V projection
  split_f32<<<nX4 / 256, blk, 0, stream>>>(value, Xhi, Xlo, nX4);
  split_f32<<<nW4 / 256, blk, 0, stream>>>(w_v, Whi, Wlo, nW4);
  gemm_split_mfma<0><<<ggemm, blk, 0, stream>>>(Xhi, Xlo, Whi, Wlo, nullptr, Vb);

  // attention -> split AO (reuses Xhi/Xlo)
  dim3 gattn(SS / 64, BB * NHEAD);  // (32, 32)
  attn_fwd<<<gattn, blk, 0, stream>>>(Qb, Kb, Vb, Xhi, Xlo);

  // O projection
  split_f32<<<nW4 / 256, blk, 0, stream>>>(w_o, Whi, Wlo, nW4);
  gemm_split_mfma<1><<<ggemm, blk, 0, stream>>>(Xhi, Xlo, Whi, Wlo, b_o, out);
}

// Round 3
// 418.549 us; speedup vs baseline: 22.8252x; 3.4854x over previous
//
#include <hip/hip_runtime.h>
#include <hip/hip_bf16.h>
#include <cstdint>

#define NHEAD 16
#define DKK 64
#define BB 2
#define SS 2048
#define DMODEL 1024

typedef __attribute__((ext_vector_type(8))) short s16x8;
typedef __attribute__((ext_vector_type(4))) float f32x4;

__device__ __forceinline__ void split1(float x, short& h, short& l) {
  __hip_bfloat16 hb = __float2bfloat16(x);
  float hf = __bfloat162float(hb);
  __hip_bfloat16 lb = __float2bfloat16(x - hf);
  h = *reinterpret_cast<short*>(&hb);
  l = *reinterpret_cast<short*>(&lb);
}

// ---------------------------------------------------------------------------
// Pre-split fp32 -> (hi, lo) bf16 pair. n4 = elements/4.
// ---------------------------------------------------------------------------
__global__ __launch_bounds__(256) void split_f32(
    const float* __restrict__ x, short* __restrict__ hi,
    short* __restrict__ lo, int n4) {
  int i = blockIdx.x * blockDim.x + threadIdx.x;
  if (i >= n4) return;
  float4 v = ((const float4*)x)[i];
  short4 h, l;
  split1(v.x, h.x, l.x);
  split1(v.y, h.y, l.y);
  split1(v.z, h.z, l.z);
  split1(v.w, h.w, l.w);
  *(short4*)&hi[i * 4] = h;
  *(short4*)&lo[i * 4] = l;
}

// ---------------------------------------------------------------------------
// Split-bf16 MFMA GEMM: Y = (Ahi+Alo) @ (Bhi+Blo)^T.
// BM=128, BN=64, BK=64, 4 waves. MFMA 16x16x32_bf16, 3 products.
// MODE 0: split bf16 out, scaled, scattered to [B,H,S,DK]   (Q, K)
// MODE 2: split bf16 out, transposed to [B,H,DK,S]          (V^T)
// MODE 1: fp32 out [M,N] + bias                             (final O proj)
// ---------------------------------------------------------------------------
template <int MODE>
__global__ __launch_bounds__(256) void gemm_split_mfma(
    const short* __restrict__ Ahi, const short* __restrict__ Alo,
    const short* __restrict__ Bhi, const short* __restrict__ Blo,
    const float* __restrict__ bias, float scale, float* __restrict__ Yf,
    short* __restrict__ Yh, short* __restrict__ Yl) {
  __shared__ short lds[(128 + 128 + 64 + 64) * 64];
  short* Ah = lds;
  short* Al = lds + 128 * 64;
  short* Bh = lds + 256 * 64;
  short* Bl = lds + 320 * 64;

  const int tid = threadIdx.x;
  const int lane = tid & 63;
  const int w = tid >> 6;
  const int wm = (w >> 1) * 64;
  const int wn = (w & 1) * 32;
  const int m0 = blockIdx.y * 128;
  const int n0 = blockIdx.x * 64;

  f32x4 acc[4][2];
#pragma unroll
  for (int r = 0; r < 4; ++r)
#pragma unroll
    for (int c = 0; c < 2; ++c) acc[r][c] = (f32x4){0.f, 0.f, 0.f, 0.f};

  for (int k0 = 0; k0 < DMODEL; k0 += 64) {
    __syncthreads();
#pragma unroll
    for (int i = 0; i < 4; ++i) {
      const int g = tid + i * 256;
      const int row = g >> 3;
      const int slot = g & 7;
      const int ssw = slot ^ (row & 7);
      const size_t goff = (size_t)(m0 + row) * DMODEL + k0 + slot * 8;
      *(s16x8*)&Ah[row * 64 + ssw * 8] = *(const s16x8*)&Ahi[goff];
      *(s16x8*)&Al[row * 64 + ssw * 8] = *(const s16x8*)&Alo[goff];
    }
#pragma unroll
    for (int i = 0; i < 2; ++i) {
      const int g = tid + i * 256;
      const int row = g >> 3;
      const int slot = g & 7;
      const int ssw = slot ^ (row & 7);
      const size_t goff = (size_t)(n0 + row) * DMODEL + k0 + slot * 8;
      *(s16x8*)&Bh[row * 64 + ssw * 8] = *(const s16x8*)&Bhi[goff];
      *(s16x8*)&Bl[row * 64 + ssw * 8] = *(const s16x8*)&Blo[goff];
    }
    __syncthreads();

#pragma unroll
    for (int ks = 0; ks < 2; ++ks) {
      const int kslot = (lane >> 4) + ks * 4;
      s16x8 ah[4], al[4], bh[2], bl[2];
#pragma unroll
      for (int r = 0; r < 4; ++r) {
        const int row = wm + r * 16 + (lane & 15);
        const int ssw = (kslot ^ (row & 7)) * 8;
        ah[r] = *(const s16x8*)&Ah[row * 64 + ssw];
        al[r] = *(const s16x8*)&Al[row * 64 + ssw];
      }
#pragma unroll
      for (int c = 0; c < 2; ++c) {
        const int row = wn + c * 16 + (lane & 15);
        const int ssw = (kslot ^ (row & 7)) * 8;
        bh[c] = *(const s16x8*)&Bh[row * 64 + ssw];
        bl[c] = *(const s16x8*)&Bl[row * 64 + ssw];
      }
#pragma unroll
      for (int r = 0; r < 4; ++r)
#pragma unroll
        for (int c = 0; c < 2; ++c) {
          acc[r][c] = __builtin_amdgcn_mfma_f32_16x16x32_bf16(al[r], bh[c], acc[r][c], 0, 0, 0);
          acc[r][c] = __builtin_amdgcn_mfma_f32_16x16x32_bf16(ah[r], bl[c], acc[r][c], 0, 0, 0);
          acc[r][c] = __builtin_amdgcn_mfma_f32_16x16x32_bf16(ah[r], bh[c], acc[r][c], 0, 0, 0);
        }
    }
  }

  // C/D: col = lane&15, row = (lane>>4)*4 + j
  const int lrow = (lane >> 4) * 4;
  const int lcol = lane & 15;
#pragma unroll
  for (int r = 0; r < 4; ++r)
#pragma unroll
    for (int c = 0; c < 2; ++c) {
      const int n = n0 + wn + c * 16 + lcol;
      if (MODE == 0) {
        const int h = n >> 6;
        const int dk = n & 63;
#pragma unroll
        for (int j = 0; j < 4; ++j) {
          const int m = m0 + wm + r * 16 + lrow + j;
          short hh, ll;
          split1(acc[r][c][j] * scale, hh, ll);
          const size_t off =
              (((size_t)((m >> 11) * NHEAD + h)) * SS + (m & (SS - 1))) * DKK + dk;
          Yh[off] = hh;
          Yl[off] = ll;
        }
      } else if (MODE == 2) {
        const int h = n >> 6;
        const int dk = n & 63;
        const int mb = m0 + wm + r * 16 + lrow;
        short4 h4, l4;
        split1(acc[r][c][0], h4.x, l4.x);
        split1(acc[r][c][1], h4.y, l4.y);
        split1(acc[r][c][2], h4.z, l4.z);
        split1(acc[r][c][3], h4.w, l4.w);
        const size_t off =
            (((size_t)((mb >> 11) * NHEAD + h)) * DKK + dk) * SS + (mb & (SS - 1));
        *(short4*)&Yh[off] = h4;
        *(short4*)&Yl[off] = l4;
      } else {
        const float bv = bias[n];
#pragma unroll
        for (int j = 0; j < 4; ++j) {
          const int m = m0 + wm + r * 16 + lrow + j;
          Yf[(size_t)m * DMODEL + n] = acc[r][c][j] + bv;
        }
      }
    }
}

// ---------------------------------------------------------------------------
// Flash attention, split-bf16 MFMA. Block = 256 thr (4 waves), 64 q-rows
// (16 per wave), kv-tiles of 64. Swapped QK^T (S^T = K @ Q^T) so each lane
// owns one q-row: softmax is in-lane + 2 shfl_xor. P -> per-wave LDS to
// re-layout C/D -> B-fragment. V consumed as V^T [B,H,DK,S] (A-operand).
// Output AO split bf16 [B,S,D] for the O-projection GEMM.
// ---------------------------------------------------------------------------
__global__ __launch_bounds__(256) void attn_mfma(
    const short* __restrict__ Qh_g, const short* __restrict__ Ql_g,
    const short* __restrict__ Kh_g, const short* __restrict__ Kl_g,
    const short* __restrict__ Vh_g, const short* __restrict__ Vl_g,
    short* __restrict__ AOh, short* __restrict__ AOl) {
  __shared__ short Ksh[64 * 64];
  __shared__ short Ksl[64 * 64];
  __shared__ short Vsh[64 * 64];
  __shared__ short Vsl[64 * 64];
  __shared__ short Psh[4][16 * 64];
  __shared__ short Psl[4][16 * 64];

  const int tid = threadIdx.x;
  const int lane = tid & 63;
  const int w = tid >> 6;
  const int col = lane & 15;
  const int g = lane >> 4;
  const int bh = blockIdx.y;
  const int q0 = blockIdx.x * 64;
  const int q = q0 + w * 16 + col;  // this lane's q row

  const size_t hb = (size_t)bh * SS * DKK;

  // Q B-fragments from global (coalesced 16B/lane), ks = 0,1
  s16x8 qbh[2], qbl[2];
#pragma unroll
  for (int ks = 0; ks < 2; ++ks) {
    const size_t off = hb + (size_t)q * DKK + g * 8 + ks * 32;
    qbh[ks] = *(const s16x8*)&Qh_g[off];
    qbl[ks] = *(const s16x8*)&Ql_g[off];
  }

  f32x4 oacc[4];
#pragma unroll
  for (int mt = 0; mt < 4; ++mt) oacc[mt] = (f32x4){0.f, 0.f, 0.f, 0.f};
  float mrun = -3.0e38f;
  float lrun = 0.0f;

  for (int kv0 = 0; kv0 < SS; kv0 += 64) {
    __syncthreads();
    // stage K-tile [64 kv][64 dk] and V^T-tile [64 d][64 kv], XOR-swizzled
#pragma unroll
    for (int i = 0; i < 2; ++i) {
      const int o = tid + i * 256;
      const int row = o >> 3;
      const int slot = o & 7;
      const int ldso = row * 64 + ((slot ^ (row & 7)) * 8);
      const size_t kg = hb + (size_t)(kv0 + row) * DKK + slot * 8;
      const size_t vg = hb + (size_t)row * SS + kv0 + slot * 8;
      *(s16x8*)&Ksh[ldso] = *(const s16x8*)&Kh_g[kg];
      *(s16x8*)&Ksl[ldso] = *(const s16x8*)&Kl_g[kg];
      *(s16x8*)&Vsh[ldso] = *(const s16x8*)&Vh_g[vg];
      *(s16x8*)&Vsl[ldso] = *(const s16x8*)&Vl_g[vg];
    }
    __syncthreads();

    // S^T[kv][q] = K @ Q^T
    f32x4 sacc[4];
#pragma unroll
    for (int mt = 0; mt < 4; ++mt) sacc[mt] = (f32x4){0.f, 0.f, 0.f, 0.f};
#pragma unroll
    for (int mt = 0; mt < 4; ++mt)
#pragma unroll
      for (int ks = 0; ks < 2; ++ks) {
        const int ar = mt * 16 + col;
        const int as = ar * 64 + (((g + ks * 4) ^ (ar & 7)) * 8);
        const s16x8 kh = *(const s16x8*)&Ksh[as];
        const s16x8 kl = *(const s16x8*)&Ksl[as];
        sacc[mt] = __builtin_amdgcn_mfma_f32_16x16x32_bf16(kh, qbl[ks], sacc[mt], 0, 0, 0);
        sacc[mt] = __builtin_amdgcn_mfma_f32_16x16x32_bf16(kl, qbh[ks], sacc[mt], 0, 0, 0);
        sacc[mt] = __builtin_amdgcn_mfma_f32_16x16x32_bf16(kh, qbh[ks], sacc[mt], 0, 0, 0);
      }

    // online softmax (lane owns q=col's row; kv = mt*16 + g*4 + j)
    float tmax = sacc[0][0];
#pragma unroll
    for (int mt = 0; mt < 4; ++mt)
#pragma unroll
      for (int j = 0; j < 4; ++j) tmax = fmaxf(tmax, sacc[mt][j]);
    tmax = fmaxf(tmax, __shfl_xor(tmax, 16, 64));
    tmax = fmaxf(tmax, __shfl_xor(tmax, 32, 64));
    const float mnew = fmaxf(mrun, tmax);
    const float corr = exp2f(mrun - mnew);
    mrun = mnew;
    float p[4][4];
    float psum = 0.f;
#pragma unroll
    for (int mt = 0; mt < 4; ++mt)
#pragma unroll
      for (int j = 0; j < 4; ++j) {
        const float e = exp2f(sacc[mt][j] - mnew);
        p[mt][j] = e;
        psum += e;
      }
    psum += __shfl_xor(psum, 16, 64);
    psum += __shfl_xor(psum, 32, 64);
    lrun = lrun * corr + psum;
#pragma unroll
    for (int mt = 0; mt < 4; ++mt) {
      oacc[mt][0] *= corr;
      oacc[mt][1] *= corr;
      oacc[mt][2] *= corr;
      oacc[mt][3] *= corr;
    }

    // P -> per-wave LDS (split bf16), layout [16 q][64 kv], 8B-slot swizzle
#pragma unroll
    for (int mt = 0; mt < 4; ++mt) {
      short4 h4, l4;
      split1(p[mt][0], h4.x, l4.x);
      split1(p[mt][1], h4.y, l4.y);
      split1(p[mt][2], h4.z, l4.z);
      split1(p[mt][3], h4.w, l4.w);
      const int slot = mt * 4 + g;
      const int off = col * 64 + ((slot ^ (col & 7)) << 2);
      *(short4*)&Psh[w][off] = h4;
      *(short4*)&Psl[w][off] = l4;
    }
    __builtin_amdgcn_wave_barrier();

    // P B-fragments: lane needs P[q=col][kv = 8g + j + 32ks]
    s16x8 pbh[2], pbl[2];
#pragma unroll
    for (int ks = 0; ks < 2; ++ks) {
      const int s0 = 2 * g + 8 * ks;
      const short4 a = *(const short4*)&Psh[w][col * 64 + ((s0 ^ (col & 7)) << 2)];
      const short4 b = *(const short4*)&Psh[w][col * 64 + (((s0 + 1) ^ (col & 7)) << 2)];
      pbh[ks] = (s16x8){a.x, a.y, a.z, a.w, b.x, b.y, b.z, b.w};
      const short4 cc = *(const short4*)&Psl[w][col * 64 + ((s0 ^ (col & 7)) << 2)];
      const short4 dd = *(const short4*)&Psl[w][col * 64 + (((s0 + 1) ^ (col & 7)) << 2)];
      pbl[ks] = (s16x8){cc.x, cc.y, cc.z, cc.w, dd.x, dd.y, dd.z, dd.w};
    }

    // O^T[d][q] += V^T @ P^T
#pragma unroll
    for (int mt = 0; mt < 4; ++mt)
#pragma unroll
      for (int ks = 0; ks < 2; ++ks) {
        const int ar = mt * 16 + col;
        const int as = ar * 64 + (((g + ks * 4) ^ (ar & 7)) * 8);
        const s16x8 vh = *(const s16x8*)&Vsh[as];
        const s16x8 vl = *(const s16x8*)&Vsl[as];
        oacc[mt] = __builtin_amdgcn_mfma_f32_16x16x32_bf16(vh, pbl[ks], oacc[mt], 0, 0, 0);
        oacc[mt] = __builtin_amdgcn_mfma_f32_16x16x32_bf16(vl, pbh[ks], oacc[mt], 0, 0, 0);
        oacc[mt] = __builtin_amdgcn_mfma_f32_16x16x32_bf16(vh, pbh[ks], oacc[mt], 0, 0, 0);
      }
  }

  // epilogue: normalize, split, write AO[B,S,D] (d = mt*16 + g*4 + j)
  const float inv = 1.0f / lrun;
  const int b = bh >> 4;
  const int h = bh & 15;
  const size_t rb = ((size_t)b * SS + q) * DMODEL + h * DKK;
#pragma unroll
  for (int mt = 0; mt < 4; ++mt) {
    short4 h4, l4;
    split1(oacc[mt][0] * inv, h4.x, l4.x);
    split1(oacc[mt][1] * inv, h4.y, l4.y);
    split1(oacc[mt][2] * inv, h4.z, l4.z);
    split1(oacc[mt][3] * inv, h4.w, l4.w);
    *(short4*)&AOh[rb + mt * 16 + g * 4] = h4;
    *(short4*)&AOl[rb + mt * 16 + g * 4] = l4;
  }
}

extern "C" void kernel_launch(void* const* d_in, const int* in_sizes, int n_in,
                              void* d_out, int out_size, void* d_ws,
                              size_t ws_size, hipStream_t stream) {
  const float* query = (const float*)d_in[0];
  const float* key   = (const float*)d_in[1];
  const float* value = (const float*)d_in[2];
  const float* w_q   = (const float*)d_in[3];
  const float* w_k   = (const float*)d_in[4];
  const float* w_v   = (const float*)d_in[5];
  const float* w_o   = (const float*)d_in[6];
  const float* b_o   = (const float*)d_in[7];
  float* out = (float*)d_out;

  const size_t per = (size_t)BB * NHEAD * SS * DKK;  // 4,194,304 elements
  short* Qbh = (short*)d_ws;
  short* Qbl = Qbh + per;
  short* Kbh = Qbl + per;
  short* Kbl = Kbh + per;
  short* Vth = Kbl + per;
  short* Vtl = Vth + per;
  short* Xhi = Vtl + per;  // doubles as AOh after V projection
  short* Xlo = Xhi + per;  // doubles as AOl
  short* Whi = Xlo + per;
  short* Wlo = Whi + (size_t)DMODEL * DMODEL;

  const int nX4 = (int)(per / 4);
  const int nW4 = (DMODEL * DMODEL) / 4;
  const float QSCALE = 0.125f * 1.4426950408889634f;  // 1/sqrt(64)*log2(e)
  dim3 blk(256);
  dim3 ggemm(DMODEL / 64, (BB * SS) / 128);  // (16, 32)

  split_f32<<<nX4 / 256, blk, 0, stream>>>(query, Xhi, Xlo, nX4);
  split_f32<<<nW4 / 256, blk, 0, stream>>>(w_q, Whi, Wlo, nW4);
  gemm_split_mfma<0><<<ggemm, blk, 0, stream>>>(Xhi, Xlo, Whi, Wlo, nullptr,
                                                QSCALE, nullptr, Qbh, Qbl);
  split_f32<<<nX4 / 256, blk, 0, stream>>>(key, Xhi, Xlo, nX4);
  split_f32<<<nW4 / 256, blk, 0, stream>>>(w_k, Whi, Wlo, nW4);
  gemm_split_mfma<0><<<ggemm, blk, 0, stream>>>(Xhi, Xlo, Whi, Wlo, nullptr,
                                                1.0f, nullptr, Kbh, Kbl);
  split_f32<<<nX4 / 256, blk, 0, stream>>>(value, Xhi, Xlo, nX4);
  split_f32<<<nW4 / 256, blk, 0, stream>>>(w_v, Whi, Wlo, nW4);
  gemm_split_mfma<2><<<ggemm, blk, 0, stream>>>(Xhi, Xlo, Whi, Wlo, nullptr,
                                                1.0f, nullptr, Vth, Vtl);

  dim3 gattn(SS / 64, BB * NHEAD);  // (32, 32)
  attn_mfma<<<gattn, blk, 0, stream>>>(Qbh, Qbl, Kbh, Kbl, Vth, Vtl, Xhi, Xlo);

  split_f32<<<nW4 / 256, blk, 0, stream>>>(w_o, Whi, Wlo, nW4);
  gemm_split_mfma<1><<<ggemm, blk, 0, stream>>>(Xhi, Xlo, Whi, Wlo, b_o, 1.0f,
                                                out, nullptr, nullptr);
}

// Round 4
// 289.976 us; speedup vs baseline: 32.9457x; 1.4434x over previous
//
#include <hip/hip_runtime.h>
#include <hip/hip_bf16.h>
#include <cstdint>

#define NHEAD 16
#define DKK 64
#define BB 2
#define SS 2048
#define DMODEL 1024

typedef __attribute__((ext_vector_type(8))) short s16x8;
typedef __attribute__((ext_vector_type(4))) float f32x4;

__device__ __forceinline__ void split1(float x, short& h, short& l) {
  __hip_bfloat16 hb = __float2bfloat16(x);
  float hf = __bfloat162float(hb);
  __hip_bfloat16 lb = __float2bfloat16(x - hf);
  h = *reinterpret_cast<short*>(&hb);
  l = *reinterpret_cast<short*>(&lb);
}

// ---------------------------------------------------------------------------
// Pre-split fp32 -> (hi, lo) bf16 pair. n4 = elements/4.
// ---------------------------------------------------------------------------
__global__ __launch_bounds__(256) void split_f32(
    const float* __restrict__ x, short* __restrict__ hi,
    short* __restrict__ lo, int n4) {
  int i = blockIdx.x * blockDim.x + threadIdx.x;
  if (i >= n4) return;
  float4 v = ((const float4*)x)[i];
  short4 h, l;
  split1(v.x, h.x, l.x);
  split1(v.y, h.y, l.y);
  split1(v.z, h.z, l.z);
  split1(v.w, h.w, l.w);
  *(short4*)&hi[i * 4] = h;
  *(short4*)&lo[i * 4] = l;
}

// ---------------------------------------------------------------------------
// Split-bf16 MFMA GEMM: Y = (Ahi+Alo) @ (Bhi+Blo)^T.  (unchanged, passing)
// MODE 0: split bf16 out, scaled, scattered to [B,H,S,DK]   (Q, K)
// MODE 2: split bf16 out, transposed to [B,H,DK,S]          (V^T)
// MODE 1: fp32 out [M,N] + bias                             (final O proj)
// ---------------------------------------------------------------------------
template <int MODE>
__global__ __launch_bounds__(256) void gemm_split_mfma(
    const short* __restrict__ Ahi, const short* __restrict__ Alo,
    const short* __restrict__ Bhi, const short* __restrict__ Blo,
    const float* __restrict__ bias, float scale, float* __restrict__ Yf,
    short* __restrict__ Yh, short* __restrict__ Yl) {
  __shared__ short lds[(128 + 128 + 64 + 64) * 64];
  short* Ah = lds;
  short* Al = lds + 128 * 64;
  short* Bh = lds + 256 * 64;
  short* Bl = lds + 320 * 64;

  const int tid = threadIdx.x;
  const int lane = tid & 63;
  const int w = tid >> 6;
  const int wm = (w >> 1) * 64;
  const int wn = (w & 1) * 32;
  const int m0 = blockIdx.y * 128;
  const int n0 = blockIdx.x * 64;

  f32x4 acc[4][2];
#pragma unroll
  for (int r = 0; r < 4; ++r)
#pragma unroll
    for (int c = 0; c < 2; ++c) acc[r][c] = (f32x4){0.f, 0.f, 0.f, 0.f};

  for (int k0 = 0; k0 < DMODEL; k0 += 64) {
    __syncthreads();
#pragma unroll
    for (int i = 0; i < 4; ++i) {
      const int g = tid + i * 256;
      const int row = g >> 3;
      const int slot = g & 7;
      const int ssw = slot ^ (row & 7);
      const size_t goff = (size_t)(m0 + row) * DMODEL + k0 + slot * 8;
      *(s16x8*)&Ah[row * 64 + ssw * 8] = *(const s16x8*)&Ahi[goff];
      *(s16x8*)&Al[row * 64 + ssw * 8] = *(const s16x8*)&Alo[goff];
    }
#pragma unroll
    for (int i = 0; i < 2; ++i) {
      const int g = tid + i * 256;
      const int row = g >> 3;
      const int slot = g & 7;
      const int ssw = slot ^ (row & 7);
      const size_t goff = (size_t)(n0 + row) * DMODEL + k0 + slot * 8;
      *(s16x8*)&Bh[row * 64 + ssw * 8] = *(const s16x8*)&Bhi[goff];
      *(s16x8*)&Bl[row * 64 + ssw * 8] = *(const s16x8*)&Blo[goff];
    }
    __syncthreads();

#pragma unroll
    for (int ks = 0; ks < 2; ++ks) {
      const int kslot = (lane >> 4) + ks * 4;
      s16x8 ah[4], al[4], bh[2], bl[2];
#pragma unroll
      for (int r = 0; r < 4; ++r) {
        const int row = wm + r * 16 + (lane & 15);
        const int ssw = (kslot ^ (row & 7)) * 8;
        ah[r] = *(const s16x8*)&Ah[row * 64 + ssw];
        al[r] = *(const s16x8*)&Al[row * 64 + ssw];
      }
#pragma unroll
      for (int c = 0; c < 2; ++c) {
        const int row = wn + c * 16 + (lane & 15);
        const int ssw = (kslot ^ (row & 7)) * 8;
        bh[c] = *(const s16x8*)&Bh[row * 64 + ssw];
        bl[c] = *(const s16x8*)&Bl[row * 64 + ssw];
      }
#pragma unroll
      for (int r = 0; r < 4; ++r)
#pragma unroll
        for (int c = 0; c < 2; ++c) {
          acc[r][c] = __builtin_amdgcn_mfma_f32_16x16x32_bf16(al[r], bh[c], acc[r][c], 0, 0, 0);
          acc[r][c] = __builtin_amdgcn_mfma_f32_16x16x32_bf16(ah[r], bl[c], acc[r][c], 0, 0, 0);
          acc[r][c] = __builtin_amdgcn_mfma_f32_16x16x32_bf16(ah[r], bh[c], acc[r][c], 0, 0, 0);
        }
    }
  }

  const int lrow = (lane >> 4) * 4;
  const int lcol = lane & 15;
#pragma unroll
  for (int r = 0; r < 4; ++r)
#pragma unroll
    for (int c = 0; c < 2; ++c) {
      const int n = n0 + wn + c * 16 + lcol;
      if (MODE == 0) {
        const int h = n >> 6;
        const int dk = n & 63;
#pragma unroll
        for (int j = 0; j < 4; ++j) {
          const int m = m0 + wm + r * 16 + lrow + j;
          short hh, ll;
          split1(acc[r][c][j] * scale, hh, ll);
          const size_t off =
              (((size_t)((m >> 11) * NHEAD + h)) * SS + (m & (SS - 1))) * DKK + dk;
          Yh[off] = hh;
          Yl[off] = ll;
        }
      } else if (MODE == 2) {
        const int h = n >> 6;
        const int dk = n & 63;
        const int mb = m0 + wm + r * 16 + lrow;
        short4 h4, l4;
        split1(acc[r][c][0], h4.x, l4.x);
        split1(acc[r][c][1], h4.y, l4.y);
        split1(acc[r][c][2], h4.z, l4.z);
        split1(acc[r][c][3], h4.w, l4.w);
        const size_t off =
            (((size_t)((mb >> 11) * NHEAD + h)) * DKK + dk) * SS + (mb & (SS - 1));
        *(short4*)&Yh[off] = h4;
        *(short4*)&Yl[off] = l4;
      } else {
        const float bv = bias[n];
#pragma unroll
        for (int j = 0; j < 4; ++j) {
          const int m = m0 + wm + r * 16 + lrow + j;
          Yf[(size_t)m * DMODEL + n] = acc[r][c][j] + bv;
        }
      }
    }
}

// ---------------------------------------------------------------------------
// Flash attention, split-bf16 MFMA, v2.
// Block = 4 waves x 32 q = 128 q rows; kv-tiles of 64. Swapped QK^T so each
// lane owns q-rows; softmax in-lane + 2 shfl. P never touches LDS: the PV
// MFMA k-order is permuted (sigma) so the lane's own C/D values ARE its
// B-fragment; V^T is staged into LDS in sigma-order (8B-chunk XOR swizzle)
// so A-fragments remain single ds_read_b128.
//   sigma(ks, g*8+e) = 32ks + 4g + 16*(e>>2) + (e&3)
//   LDS chunk(8B) index for kv: c = (kv>>5)*8 + ((kv>>2)&3)*2 + ((kv>>4)&1)
//   swizzle: c ^= (row&7)<<1
// XCD-chunked bijective block remap: 16 q-blocks of one head stay on 1 XCD.
// ---------------------------------------------------------------------------
__global__ __launch_bounds__(256) void attn_mfma(
    const short* __restrict__ Qh_g, const short* __restrict__ Ql_g,
    const short* __restrict__ Kh_g, const short* __restrict__ Kl_g,
    const short* __restrict__ Vh_g, const short* __restrict__ Vl_g,
    short* __restrict__ AOh, short* __restrict__ AOl) {
  __shared__ short Ksh[64 * 64];
  __shared__ short Ksl[64 * 64];
  __shared__ short Vsh[64 * 64];
  __shared__ short Vsl[64 * 64];

  const int tid = threadIdx.x;
  const int lane = tid & 63;
  const int w = tid >> 6;
  const int col = lane & 15;
  const int g = lane >> 4;

  // bijective XCD remap: 512 blocks, chunk = 64 per XCD = 4 whole heads
  const int flat = blockIdx.y * gridDim.x + blockIdx.x;
  const int remap = (flat & 7) * 64 + (flat >> 3);
  const int bh = remap >> 4;           // 0..31
  const int q0 = (remap & 15) * 128;   // q-block of 128

  const size_t hb = (size_t)bh * SS * DKK;

  // Q B-fragments for the wave's 32 q rows (2 sets of 16)
  s16x8 qbh[2][2], qbl[2][2];
#pragma unroll
  for (int qq = 0; qq < 2; ++qq)
#pragma unroll
    for (int ks = 0; ks < 2; ++ks) {
      const size_t off =
          hb + (size_t)(q0 + w * 32 + qq * 16 + col) * DKK + g * 8 + ks * 32;
      qbh[qq][ks] = *(const s16x8*)&Qh_g[off];
      qbl[qq][ks] = *(const s16x8*)&Ql_g[off];
    }

  f32x4 oacc[2][4];
#pragma unroll
  for (int qq = 0; qq < 2; ++qq)
#pragma unroll
    for (int mt = 0; mt < 4; ++mt) oacc[qq][mt] = (f32x4){0.f, 0.f, 0.f, 0.f};
  float mrun[2] = {-1e30f, -1e30f};
  float lrun[2] = {0.f, 0.f};

  for (int kv0 = 0; kv0 < SS; kv0 += 64) {
    __syncthreads();
    // ---- stage K (standard swizzled) and V^T (sigma-order, 8B swizzle) ----
#pragma unroll
    for (int i = 0; i < 2; ++i) {
      const int o = tid + i * 256;
      const int row = o >> 3;
      const int slot = o & 7;
      // K tile: [kv row][dk]
      const int kds = row * 64 + ((slot ^ (row & 7)) * 8);
      const size_t kg = hb + (size_t)(kv0 + row) * DKK + slot * 8;
      *(s16x8*)&Ksh[kds] = *(const s16x8*)&Kh_g[kg];
      *(s16x8*)&Ksl[kds] = *(const s16x8*)&Kl_g[kg];
      // V^T tile: [d row][kv] -> sigma positions, two b64 scatter writes
      const size_t vg = hb + (size_t)row * SS + kv0 + slot * 8;
      const s16x8 vh = *(const s16x8*)&Vh_g[vg];
      const s16x8 vl = *(const s16x8*)&Vl_g[vg];
      const int sw = (row & 7) << 1;
      const int cA = ((slot >> 2) * 8 + ((2 * slot) & 3) * 2 + ((slot >> 1) & 1)) ^ sw;
      const int cB = ((slot >> 2) * 8 + ((2 * slot + 1) & 3) * 2 + ((slot >> 1) & 1)) ^ sw;
      *(short4*)&Vsh[row * 64 + cA * 4] = (short4){vh[0], vh[1], vh[2], vh[3]};
      *(short4*)&Vsh[row * 64 + cB * 4] = (short4){vh[4], vh[5], vh[6], vh[7]};
      *(short4*)&Vsl[row * 64 + cA * 4] = (short4){vl[0], vl[1], vl[2], vl[3]};
      *(short4*)&Vsl[row * 64 + cB * 4] = (short4){vl[4], vl[5], vl[6], vl[7]};
    }
    __syncthreads();

    // ---- S^T = K @ Q^T ----
    f32x4 sacc[2][4];
#pragma unroll
    for (int qq = 0; qq < 2; ++qq)
#pragma unroll
      for (int mt = 0; mt < 4; ++mt) sacc[qq][mt] = (f32x4){0.f, 0.f, 0.f, 0.f};
#pragma unroll
    for (int mt = 0; mt < 4; ++mt) {
      const int ar = mt * 16 + col;
#pragma unroll
      for (int ks = 0; ks < 2; ++ks) {
        const int as = ar * 64 + (((g + 4 * ks) ^ (ar & 7)) * 8);
        const s16x8 kh = *(const s16x8*)&Ksh[as];
        const s16x8 kl = *(const s16x8*)&Ksl[as];
#pragma unroll
        for (int qq = 0; qq < 2; ++qq) {
          sacc[qq][mt] = __builtin_amdgcn_mfma_f32_16x16x32_bf16(kh, qbl[qq][ks], sacc[qq][mt], 0, 0, 0);
          sacc[qq][mt] = __builtin_amdgcn_mfma_f32_16x16x32_bf16(kl, qbh[qq][ks], sacc[qq][mt], 0, 0, 0);
          sacc[qq][mt] = __builtin_amdgcn_mfma_f32_16x16x32_bf16(kh, qbh[qq][ks], sacc[qq][mt], 0, 0, 0);
        }
      }
    }

    // ---- online softmax (lane owns rows; reduce across g via shfl) ----
#pragma unroll
    for (int qq = 0; qq < 2; ++qq) {
      float tmax = sacc[qq][0][0];
#pragma unroll
      for (int mt = 0; mt < 4; ++mt)
#pragma unroll
        for (int j = 0; j < 4; ++j) tmax = fmaxf(tmax, sacc[qq][mt][j]);
      tmax = fmaxf(tmax, __shfl_xor(tmax, 16, 64));
      tmax = fmaxf(tmax, __shfl_xor(tmax, 32, 64));
      const float mnew = fmaxf(mrun[qq], tmax);
      const float corr = exp2f(mrun[qq] - mnew);
      mrun[qq] = mnew;
      float psum = 0.f;
#pragma unroll
      for (int mt = 0; mt < 4; ++mt)
#pragma unroll
        for (int j = 0; j < 4; ++j) {
          const float e = exp2f(sacc[qq][mt][j] - mnew);
          sacc[qq][mt][j] = e;
          psum += e;
        }
      psum += __shfl_xor(psum, 16, 64);
      psum += __shfl_xor(psum, 32, 64);
      lrun[qq] = lrun[qq] * corr + psum;
#pragma unroll
      for (int mt = 0; mt < 4; ++mt) {
        oacc[qq][mt][0] *= corr;
        oacc[qq][mt][1] *= corr;
        oacc[qq][mt][2] *= corr;
        oacc[qq][mt][3] *= corr;
      }
    }

    // ---- pack P into B-fragments in-register (sigma k-order) ----
    // pb[qq][ks][e] = P at kv = 16*(2ks+(e>>2)) + 4g + (e&3) = sacc[qq][2ks+(e>>2)][e&3]
    s16x8 pbh[2][2], pbl[2][2];
#pragma unroll
    for (int qq = 0; qq < 2; ++qq)
#pragma unroll
      for (int ks = 0; ks < 2; ++ks) {
        s16x8 ph, pl;
#pragma unroll
        for (int e = 0; e < 8; ++e) {
          short hh, ll;
          split1(sacc[qq][2 * ks + (e >> 2)][e & 3], hh, ll);
          ph[e] = hh;
          pl[e] = ll;
        }
        pbh[qq][ks] = ph;
        pbl[qq][ks] = pl;
      }

    // ---- O^T += V^T @ P^T (sigma-consistent A-fragments from LDS) ----
#pragma unroll
    for (int mt = 0; mt < 4; ++mt) {
      const int row = mt * 16 + col;
      const int sw = (row & 7) << 1;
#pragma unroll
      for (int ks = 0; ks < 2; ++ks) {
        const int c0 = (8 * ks + 2 * g) ^ sw;
        const s16x8 vh = *(const s16x8*)&Vsh[row * 64 + c0 * 4];
        const s16x8 vl = *(const s16x8*)&Vsl[row * 64 + c0 * 4];
#pragma unroll
        for (int qq = 0; qq < 2; ++qq) {
          oacc[qq][mt] = __builtin_amdgcn_mfma_f32_16x16x32_bf16(vh, pbl[qq][ks], oacc[qq][mt], 0, 0, 0);
          oacc[qq][mt] = __builtin_amdgcn_mfma_f32_16x16x32_bf16(vl, pbh[qq][ks], oacc[qq][mt], 0, 0, 0);
          oacc[qq][mt] = __builtin_amdgcn_mfma_f32_16x16x32_bf16(vh, pbh[qq][ks], oacc[qq][mt], 0, 0, 0);
        }
      }
    }
  }

  // ---- epilogue: normalize, split, write AO[B,S,D] ----
  const int b = bh >> 4;
  const int h = bh & 15;
#pragma unroll
  for (int qq = 0; qq < 2; ++qq) {
    const float inv = 1.0f / lrun[qq];
    const int q = q0 + w * 32 + qq * 16 + col;
    const size_t rb = ((size_t)b * SS + q) * DMODEL + h * DKK;
#pragma unroll
    for (int mt = 0; mt < 4; ++mt) {
      short4 h4, l4;
      split1(oacc[qq][mt][0] * inv, h4.x, l4.x);
      split1(oacc[qq][mt][1] * inv, h4.y, l4.y);
      split1(oacc[qq][mt][2] * inv, h4.z, l4.z);
      split1(oacc[qq][mt][3] * inv, h4.w, l4.w);
      *(short4*)&AOh[rb + mt * 16 + g * 4] = h4;
      *(short4*)&AOl[rb + mt * 16 + g * 4] = l4;
    }
  }
}

extern "C" void kernel_launch(void* const* d_in, const int* in_sizes, int n_in,
                              void* d_out, int out_size, void* d_ws,
                              size_t ws_size, hipStream_t stream) {
  const float* query = (const float*)d_in[0];
  const float* key   = (const float*)d_in[1];
  const float* value = (const float*)d_in[2];
  const float* w_q   = (const float*)d_in[3];
  const float* w_k   = (const float*)d_in[4];
  const float* w_v   = (const float*)d_in[5];
  const float* w_o   = (const float*)d_in[6];
  const float* b_o   = (const float*)d_in[7];
  float* out = (float*)d_out;

  const size_t per = (size_t)BB * NHEAD * SS * DKK;  // 4,194,304 elements
  short* Qbh = (short*)d_ws;
  short* Qbl = Qbh + per;
  short* Kbh = Qbl + per;
  short* Kbl = Kbh + per;
  short* Vth = Kbl + per;
  short* Vtl = Vth + per;
  short* Xhi = Vtl + per;  // doubles as AOh after V projection
  short* Xlo = Xhi + per;  // doubles as AOl
  short* Whi = Xlo + per;
  short* Wlo = Whi + (size_t)DMODEL * DMODEL;

  const int nX4 = (int)(per / 4);
  const int nW4 = (DMODEL * DMODEL) / 4;
  const float QSCALE = 0.125f * 1.4426950408889634f;  // 1/sqrt(64)*log2(e)
  dim3 blk(256);
  dim3 ggemm(DMODEL / 64, (BB * SS) / 128);  // (16, 32)

  split_f32<<<nX4 / 256, blk, 0, stream>>>(query, Xhi, Xlo, nX4);
  split_f32<<<nW4 / 256, blk, 0, stream>>>(w_q, Whi, Wlo, nW4);
  gemm_split_mfma<0><<<ggemm, blk, 0, stream>>>(Xhi, Xlo, Whi, Wlo, nullptr,
                                                QSCALE, nullptr, Qbh, Qbl);
  split_f32<<<nX4 / 256, blk, 0, stream>>>(key, Xhi, Xlo, nX4);
  split_f32<<<nW4 / 256, blk, 0, stream>>>(w_k, Whi, Wlo, nW4);
  gemm_split_mfma<0><<<ggemm, blk, 0, stream>>>(Xhi, Xlo, Whi, Wlo, nullptr,
                                                1.0f, nullptr, Kbh, Kbl);
  split_f32<<<nX4 / 256, blk, 0, stream>>>(value, Xhi, Xlo, nX4);
  split_f32<<<nW4 / 256, blk, 0, stream>>>(w_v, Whi, Wlo, nW4);
  gemm_split_mfma<2><<<ggemm, blk, 0, stream>>>(Xhi, Xlo, Whi, Wlo, nullptr,
                                                1.0f, nullptr, Vth, Vtl);

  dim3 gattn(SS / 128, BB * NHEAD);  // (16, 32) = 512 blocks
  attn_mfma<<<gattn, blk, 0, stream>>>(Qbh, Qbl, Kbh, Kbl, Vth, Vtl, Xhi, Xlo);

  split_f32<<<nW4 / 256, blk, 0, stream>>>(w_o, Whi, Wlo, nW4);
  gemm_split_mfma<1><<<ggemm, blk, 0, stream>>>(Xhi, Xlo, Whi, Wlo, b_o, 1.0f,
                                                out, nullptr, nullptr);
}

// Round 5
// 270.379 us; speedup vs baseline: 35.3336x; 1.0725x over previous
//
#include <hip/hip_runtime.h>
#include <hip/hip_bf16.h>
#include <cstdint>

#define NHEAD 16
#define DKK 64
#define BB 2
#define SS 2048
#define DMODEL 1024

typedef __attribute__((ext_vector_type(8))) short s16x8;
typedef __attribute__((ext_vector_type(4))) float f32x4;

__device__ __forceinline__ void split1(float x, short& h, short& l) {
  __hip_bfloat16 hb = __float2bfloat16(x);
  float hf = __bfloat162float(hb);
  __hip_bfloat16 lb = __float2bfloat16(x - hf);
  h = *reinterpret_cast<short*>(&hb);
  l = *reinterpret_cast<short*>(&lb);
}

__device__ __forceinline__ short bf16s(float x) {
  __hip_bfloat16 b = __float2bfloat16(x);
  return *reinterpret_cast<short*>(&b);
}

// ---------------------------------------------------------------------------
// Pre-split fp32 -> (hi, lo) bf16 pair. n4 = elements/4.
// ---------------------------------------------------------------------------
__global__ __launch_bounds__(256) void split_f32(
    const float* __restrict__ x, short* __restrict__ hi,
    short* __restrict__ lo, int n4) {
  int i = blockIdx.x * blockDim.x + threadIdx.x;
  if (i >= n4) return;
  float4 v = ((const float4*)x)[i];
  short4 h, l;
  split1(v.x, h.x, l.x);
  split1(v.y, h.y, l.y);
  split1(v.z, h.z, l.z);
  split1(v.w, h.w, l.w);
  *(short4*)&hi[i * 4] = h;
  *(short4*)&lo[i * 4] = l;
}

// ---------------------------------------------------------------------------
// Split-bf16 MFMA GEMM: Y = (Ahi+Alo) @ (Bhi+Blo)^T.
// MODE 0: split bf16 out, scaled, scattered to [B,H,S,DK]   (Q, K)
// MODE 2: bf16 HI-ONLY out, sigma-permuted transpose [B,H,DK,S]  (V^T)
// MODE 1: fp32 out [M,N] + bias                             (final O proj)
// ---------------------------------------------------------------------------
template <int MODE>
__global__ __launch_bounds__(256) void gemm_split_mfma(
    const short* __restrict__ Ahi, const short* __restrict__ Alo,
    const short* __restrict__ Bhi, const short* __restrict__ Blo,
    const float* __restrict__ bias, float scale, float* __restrict__ Yf,
    short* __restrict__ Yh, short* __restrict__ Yl) {
  __shared__ short lds[(128 + 128 + 64 + 64) * 64];
  short* Ah = lds;
  short* Al = lds + 128 * 64;
  short* Bh = lds + 256 * 64;
  short* Bl = lds + 320 * 64;

  const int tid = threadIdx.x;
  const int lane = tid & 63;
  const int w = tid >> 6;
  const int wm = (w >> 1) * 64;
  const int wn = (w & 1) * 32;
  const int m0 = blockIdx.y * 128;
  const int n0 = blockIdx.x * 64;

  f32x4 acc[4][2];
#pragma unroll
  for (int r = 0; r < 4; ++r)
#pragma unroll
    for (int c = 0; c < 2; ++c) acc[r][c] = (f32x4){0.f, 0.f, 0.f, 0.f};

  for (int k0 = 0; k0 < DMODEL; k0 += 64) {
    __syncthreads();
#pragma unroll
    for (int i = 0; i < 4; ++i) {
      const int g = tid + i * 256;
      const int row = g >> 3;
      const int slot = g & 7;
      const int ssw = slot ^ (row & 7);
      const size_t goff = (size_t)(m0 + row) * DMODEL + k0 + slot * 8;
      *(s16x8*)&Ah[row * 64 + ssw * 8] = *(const s16x8*)&Ahi[goff];
      *(s16x8*)&Al[row * 64 + ssw * 8] = *(const s16x8*)&Alo[goff];
    }
#pragma unroll
    for (int i = 0; i < 2; ++i) {
      const int g = tid + i * 256;
      const int row = g >> 3;
      const int slot = g & 7;
      const int ssw = slot ^ (row & 7);
      const size_t goff = (size_t)(n0 + row) * DMODEL + k0 + slot * 8;
      *(s16x8*)&Bh[row * 64 + ssw * 8] = *(const s16x8*)&Bhi[goff];
      *(s16x8*)&Bl[row * 64 + ssw * 8] = *(const s16x8*)&Blo[goff];
    }
    __syncthreads();

#pragma unroll
    for (int ks = 0; ks < 2; ++ks) {
      const int kslot = (lane >> 4) + ks * 4;
      s16x8 ah[4], al[4], bh[2], bl[2];
#pragma unroll
      for (int r = 0; r < 4; ++r) {
        const int row = wm + r * 16 + (lane & 15);
        const int ssw = (kslot ^ (row & 7)) * 8;
        ah[r] = *(const s16x8*)&Ah[row * 64 + ssw];
        al[r] = *(const s16x8*)&Al[row * 64 + ssw];
      }
#pragma unroll
      for (int c = 0; c < 2; ++c) {
        const int row = wn + c * 16 + (lane & 15);
        const int ssw = (kslot ^ (row & 7)) * 8;
        bh[c] = *(const s16x8*)&Bh[row * 64 + ssw];
        bl[c] = *(const s16x8*)&Bl[row * 64 + ssw];
      }
#pragma unroll
      for (int r = 0; r < 4; ++r)
#pragma unroll
        for (int c = 0; c < 2; ++c) {
          acc[r][c] = __builtin_amdgcn_mfma_f32_16x16x32_bf16(al[r], bh[c], acc[r][c], 0, 0, 0);
          acc[r][c] = __builtin_amdgcn_mfma_f32_16x16x32_bf16(ah[r], bl[c], acc[r][c], 0, 0, 0);
          acc[r][c] = __builtin_amdgcn_mfma_f32_16x16x32_bf16(ah[r], bh[c], acc[r][c], 0, 0, 0);
        }
    }
  }

  const int lrow = (lane >> 4) * 4;
  const int lcol = lane & 15;
#pragma unroll
  for (int r = 0; r < 4; ++r)
#pragma unroll
    for (int c = 0; c < 2; ++c) {
      const int n = n0 + wn + c * 16 + lcol;
      if (MODE == 0) {
        const int h = n >> 6;
        const int dk = n & 63;
#pragma unroll
        for (int j = 0; j < 4; ++j) {
          const int m = m0 + wm + r * 16 + lrow + j;
          short hh, ll;
          split1(acc[r][c][j] * scale, hh, ll);
          const size_t off =
              (((size_t)((m >> 11) * NHEAD + h)) * SS + (m & (SS - 1))) * DKK + dk;
          Yh[off] = hh;
          Yl[off] = ll;
        }
      } else if (MODE == 2) {
        const int h = n >> 6;
        const int dk = n & 63;
        const int mb = m0 + wm + r * 16 + lrow;
        short4 h4;
        h4.x = bf16s(acc[r][c][0]);
        h4.y = bf16s(acc[r][c][1]);
        h4.z = bf16s(acc[r][c][2]);
        h4.w = bf16s(acc[r][c][3]);
        const size_t off =
            (((size_t)((mb >> 11) * NHEAD + h)) * DKK + dk) * SS + (mb & (SS - 1));
        *(short4*)&Yh[off] = h4;
      } else {
        const float bv = bias[n];
#pragma unroll
        for (int j = 0; j < 4; ++j) {
          const int m = m0 + wm + r * 16 + lrow + j;
          Yf[(size_t)m * DMODEL + n] = acc[r][c][j] + bv;
        }
      }
    }
}

// ---------------------------------------------------------------------------
// Flash attention, split-bf16 MFMA, v3.
// 4 waves x 32 q = 128 q rows/block; kv-tiles of 64; swapped QK^T; sigma
// k-order PV (P stays in registers). V is bf16 HI-ONLY (PV = vh*(pbl+pbh)).
// Double-buffered LDS, async-stage split (global->reg early, ds_write late),
// ONE barrier per tile. Defer-max rescale (THR=8, base-2).
// ---------------------------------------------------------------------------
__global__ __launch_bounds__(256) void attn_mfma(
    const short* __restrict__ Qh_g, const short* __restrict__ Ql_g,
    const short* __restrict__ Kh_g, const short* __restrict__ Kl_g,
    const short* __restrict__ Vh_g,
    short* __restrict__ AOh, short* __restrict__ AOl) {
  __shared__ short Ksh[2][64 * 64];
  __shared__ short Ksl[2][64 * 64];
  __shared__ short Vsh[2][64 * 64];

  const int tid = threadIdx.x;
  const int lane = tid & 63;
  const int w = tid >> 6;
  const int col = lane & 15;
  const int g = lane >> 4;

  // bijective XCD remap: 512 blocks, 64/XCD = 4 whole heads per XCD
  const int flat = blockIdx.y * gridDim.x + blockIdx.x;
  const int remap = (flat & 7) * 64 + (flat >> 3);
  const int bh = remap >> 4;
  const int q0 = (remap & 15) * 128;

  const size_t hb = (size_t)bh * SS * DKK;

  // staging geometry (2 chunks per thread, slot identical for both)
  const int row0 = tid >> 3, row1 = (tid + 256) >> 3;
  const int slot = tid & 7;
  const int kds0 = row0 * 64 + ((slot ^ (row0 & 7)) * 8);
  const int kds1 = row1 * 64 + ((slot ^ (row1 & 7)) * 8);
  const int baseA = (slot >> 2) * 8 + ((2 * slot) & 3) * 2 + ((slot >> 1) & 1);
  const int baseB = (slot >> 2) * 8 + ((2 * slot + 1) & 3) * 2 + ((slot >> 1) & 1);
  const int sw0 = (row0 & 7) << 1, sw1 = (row1 & 7) << 1;
  const int vA0 = row0 * 64 + (baseA ^ sw0) * 4;
  const int vB0 = row0 * 64 + (baseB ^ sw0) * 4;
  const int vA1 = row1 * 64 + (baseA ^ sw1) * 4;
  const int vB1 = row1 * 64 + (baseB ^ sw1) * 4;

  // Q B-fragments (loop-invariant)
  s16x8 qbh[2][2], qbl[2][2];
#pragma unroll
  for (int qq = 0; qq < 2; ++qq)
#pragma unroll
    for (int ks = 0; ks < 2; ++ks) {
      const size_t off =
          hb + (size_t)(q0 + w * 32 + qq * 16 + col) * DKK + g * 8 + ks * 32;
      qbh[qq][ks] = *(const s16x8*)&Qh_g[off];
      qbl[qq][ks] = *(const s16x8*)&Ql_g[off];
    }

  f32x4 oacc[2][4];
#pragma unroll
  for (int qq = 0; qq < 2; ++qq)
#pragma unroll
    for (int mt = 0; mt < 4; ++mt) oacc[qq][mt] = (f32x4){0.f, 0.f, 0.f, 0.f};
  float mrun[2] = {-1e30f, -1e30f};
  float lrun[2] = {0.f, 0.f};

  // staging registers (named, no dynamic indexing)
  s16x8 nkh0, nkl0, nvh0, nkh1, nkl1, nvh1;

#define LOAD_TILE(KV0)                                                        \
  {                                                                           \
    const int kv0_ = (KV0);                                                   \
    nkh0 = *(const s16x8*)&Kh_g[hb + (size_t)(kv0_ + row0) * DKK + slot * 8]; \
    nkl0 = *(const s16x8*)&Kl_g[hb + (size_t)(kv0_ + row0) * DKK + slot * 8]; \
    nkh1 = *(const s16x8*)&Kh_g[hb + (size_t)(kv0_ + row1) * DKK + slot * 8]; \
    nkl1 = *(const s16x8*)&Kl_g[hb + (size_t)(kv0_ + row1) * DKK + slot * 8]; \
    nvh0 = *(const s16x8*)&Vh_g[hb + (size_t)row0 * SS + kv0_ + slot * 8];    \
    nvh1 = *(const s16x8*)&Vh_g[hb + (size_t)row1 * SS + kv0_ + slot * 8];    \
  }

#define WRITE_TILE(BUF)                                                       \
  {                                                                           \
    *(s16x8*)&Ksh[BUF][kds0] = nkh0;                                          \
    *(s16x8*)&Ksl[BUF][kds0] = nkl0;                                          \
    *(s16x8*)&Ksh[BUF][kds1] = nkh1;                                          \
    *(s16x8*)&Ksl[BUF][kds1] = nkl1;                                          \
    *(short4*)&Vsh[BUF][vA0] = (short4){nvh0[0], nvh0[1], nvh0[2], nvh0[3]};  \
    *(short4*)&Vsh[BUF][vB0] = (short4){nvh0[4], nvh0[5], nvh0[6], nvh0[7]};  \
    *(short4*)&Vsh[BUF][vA1] = (short4){nvh1[0], nvh1[1], nvh1[2], nvh1[3]};  \
    *(short4*)&Vsh[BUF][vB1] = (short4){nvh1[4], nvh1[5], nvh1[6], nvh1[7]};  \
  }

  LOAD_TILE(0);
  WRITE_TILE(0);
  __syncthreads();

  int cur = 0;
  constexpr int NT = SS / 64;
  for (int t = 0; t < NT; ++t) {
    if (t < NT - 1) LOAD_TILE((t + 1) * 64);

    const short* kb_h = &Ksh[cur][0];
    const short* kb_l = &Ksl[cur][0];
    const short* vb_h = &Vsh[cur][0];

    // ---- S^T = K @ Q^T (3 products) ----
    f32x4 sacc[2][4];
#pragma unroll
    for (int qq = 0; qq < 2; ++qq)
#pragma unroll
      for (int mt = 0; mt < 4; ++mt) sacc[qq][mt] = (f32x4){0.f, 0.f, 0.f, 0.f};
#pragma unroll
    for (int mt = 0; mt < 4; ++mt) {
      const int ar = mt * 16 + col;
#pragma unroll
      for (int ks = 0; ks < 2; ++ks) {
        const int as = ar * 64 + (((g + 4 * ks) ^ (ar & 7)) * 8);
        const s16x8 kh = *(const s16x8*)&kb_h[as];
        const s16x8 kl = *(const s16x8*)&kb_l[as];
#pragma unroll
        for (int qq = 0; qq < 2; ++qq) {
          sacc[qq][mt] = __builtin_amdgcn_mfma_f32_16x16x32_bf16(kh, qbl[qq][ks], sacc[qq][mt], 0, 0, 0);
          sacc[qq][mt] = __builtin_amdgcn_mfma_f32_16x16x32_bf16(kl, qbh[qq][ks], sacc[qq][mt], 0, 0, 0);
          sacc[qq][mt] = __builtin_amdgcn_mfma_f32_16x16x32_bf16(kh, qbh[qq][ks], sacc[qq][mt], 0, 0, 0);
        }
      }
    }

    // ---- online softmax with defer-max (THR = 8 in base-2 units) ----
#pragma unroll
    for (int qq = 0; qq < 2; ++qq) {
      float tmax = sacc[qq][0][0];
#pragma unroll
      for (int mt = 0; mt < 4; ++mt)
#pragma unroll
        for (int j = 0; j < 4; ++j) tmax = fmaxf(tmax, sacc[qq][mt][j]);
      tmax = fmaxf(tmax, __shfl_xor(tmax, 16, 64));
      tmax = fmaxf(tmax, __shfl_xor(tmax, 32, 64));
      const float d = tmax - mrun[qq];
      const bool need = d > 8.0f;
      if (__any(need)) {
        const float corr = need ? exp2f(-d) : 1.0f;
        mrun[qq] = need ? tmax : mrun[qq];
        lrun[qq] *= corr;
#pragma unroll
        for (int mt = 0; mt < 4; ++mt) {
          oacc[qq][mt][0] *= corr;
          oacc[qq][mt][1] *= corr;
          oacc[qq][mt][2] *= corr;
          oacc[qq][mt][3] *= corr;
        }
      }
      float psum = 0.f;
#pragma unroll
      for (int mt = 0; mt < 4; ++mt)
#pragma unroll
        for (int j = 0; j < 4; ++j) {
          const float e = exp2f(sacc[qq][mt][j] - mrun[qq]);
          sacc[qq][mt][j] = e;
          psum += e;
        }
      psum += __shfl_xor(psum, 16, 64);
      psum += __shfl_xor(psum, 32, 64);
      lrun[qq] += psum;
    }

    // ---- pack P into split-bf16 B-fragments (sigma k-order, in-register) ----
    s16x8 pbh[2][2], pbl[2][2];
#pragma unroll
    for (int qq = 0; qq < 2; ++qq)
#pragma unroll
      for (int ks = 0; ks < 2; ++ks) {
        s16x8 ph, pl;
#pragma unroll
        for (int e = 0; e < 8; ++e) {
          short hh, ll;
          split1(sacc[qq][2 * ks + (e >> 2)][e & 3], hh, ll);
          ph[e] = hh;
          pl[e] = ll;
        }
        pbh[qq][ks] = ph;
        pbl[qq][ks] = pl;
      }

    // ---- O^T += V^T_hi @ (P_lo + P_hi)^T ----
#pragma unroll
    for (int mt = 0; mt < 4; ++mt) {
      const int row = mt * 16 + col;
      const int sw = (row & 7) << 1;
#pragma unroll
      for (int ks = 0; ks < 2; ++ks) {
        const int c0 = (8 * ks + 2 * g) ^ sw;
        const s16x8 vh = *(const s16x8*)&vb_h[row * 64 + c0 * 4];
#pragma unroll
        for (int qq = 0; qq < 2; ++qq) {
          oacc[qq][mt] = __builtin_amdgcn_mfma_f32_16x16x32_bf16(vh, pbl[qq][ks], oacc[qq][mt], 0, 0, 0);
          oacc[qq][mt] = __builtin_amdgcn_mfma_f32_16x16x32_bf16(vh, pbh[qq][ks], oacc[qq][mt], 0, 0, 0);
        }
      }
    }

    if (t < NT - 1) WRITE_TILE(cur ^ 1);
    __syncthreads();
    cur ^= 1;
  }

  // ---- epilogue: normalize, split, write AO[B,S,D] ----
  const int b = bh >> 4;
  const int h = bh & 15;
#pragma unroll
  for (int qq = 0; qq < 2; ++qq) {
    const float inv = 1.0f / lrun[qq];
    const int q = q0 + w * 32 + qq * 16 + col;
    const size_t rb = ((size_t)b * SS + q) * DMODEL + h * DKK;
#pragma unroll
    for (int mt = 0; mt < 4; ++mt) {
      short4 h4, l4;
      split1(oacc[qq][mt][0] * inv, h4.x, l4.x);
      split1(oacc[qq][mt][1] * inv, h4.y, l4.y);
      split1(oacc[qq][mt][2] * inv, h4.z, l4.z);
      split1(oacc[qq][mt][3] * inv, h4.w, l4.w);
      *(short4*)&AOh[rb + mt * 16 + g * 4] = h4;
      *(short4*)&AOl[rb + mt * 16 + g * 4] = l4;
    }
  }
#undef LOAD_TILE
#undef WRITE_TILE
}

extern "C" void kernel_launch(void* const* d_in, const int* in_sizes, int n_in,
                              void* d_out, int out_size, void* d_ws,
                              size_t ws_size, hipStream_t stream) {
  const float* query = (const float*)d_in[0];
  const float* key   = (const float*)d_in[1];
  const float* value = (const float*)d_in[2];
  const float* w_q   = (const float*)d_in[3];
  const float* w_k   = (const float*)d_in[4];
  const float* w_v   = (const float*)d_in[5];
  const float* w_o   = (const float*)d_in[6];
  const float* b_o   = (const float*)d_in[7];
  float* out = (float*)d_out;

  const size_t per = (size_t)BB * NHEAD * SS * DKK;  // 4,194,304 elements
  short* Qbh = (short*)d_ws;
  short* Qbl = Qbh + per;
  short* Kbh = Qbl + per;
  short* Kbl = Kbh + per;
  short* Vth = Kbl + per;        // V^T hi only
  short* Xhi = Vth + per;        // doubles as AOh after attention
  short* Xlo = Xhi + per;        // doubles as AOl
  short* Whi = Xlo + per;
  short* Wlo = Whi + (size_t)DMODEL * DMODEL;

  const int nX4 = (int)(per / 4);
  const int nW4 = (DMODEL * DMODEL) / 4;
  const float QSCALE = 0.125f * 1.4426950408889634f;  // 1/sqrt(64)*log2(e)
  dim3 blk(256);
  dim3 ggemm(DMODEL / 64, (BB * SS) / 128);  // (16, 32)

  split_f32<<<nX4 / 256, blk, 0, stream>>>(query, Xhi, Xlo, nX4);
  split_f32<<<nW4 / 256, blk, 0, stream>>>(w_q, Whi, Wlo, nW4);
  gemm_split_mfma<0><<<ggemm, blk, 0, stream>>>(Xhi, Xlo, Whi, Wlo, nullptr,
                                                QSCALE, nullptr, Qbh, Qbl);
  split_f32<<<nX4 / 256, blk, 0, stream>>>(key, Xhi, Xlo, nX4);
  split_f32<<<nW4 / 256, blk, 0, stream>>>(w_k, Whi, Wlo, nW4);
  gemm_split_mfma<0><<<ggemm, blk, 0, stream>>>(Xhi, Xlo, Whi, Wlo, nullptr,
                                                1.0f, nullptr, Kbh, Kbl);
  split_f32<<<nX4 / 256, blk, 0, stream>>>(value, Xhi, Xlo, nX4);
  split_f32<<<nW4 / 256, blk, 0, stream>>>(w_v, Whi, Wlo, nW4);
  gemm_split_mfma<2><<<ggemm, blk, 0, stream>>>(Xhi, Xlo, Whi, Wlo, nullptr,
                                                1.0f, nullptr, Vth, nullptr);

  dim3 gattn(SS / 128, BB * NHEAD);  // (16, 32) = 512 blocks
  attn_mfma<<<gattn, blk, 0, stream>>>(Qbh, Qbl, Kbh, Kbl, Vth, Xhi, Xlo);

  split_f32<<<nW4 / 256, blk, 0, stream>>>(w_o, Whi, Wlo, nW4);
  gemm_split_mfma<1><<<ggemm, blk, 0, stream>>>(Xhi, Xlo, Whi, Wlo, b_o, 1.0f,
                                                out, nullptr, nullptr);
}